// Round 7
// baseline (8349.958 us; speedup 1.0000x reference)
//
#include <hip/hip_runtime.h>
#include <hip/hip_bf16.h>
#include <stdint.h>

#define BB 512
#define LL 77
#define DD 512
#define HH 8
#define NLAYER 12
#define NTOK (BB*LL)        // 39424 = 154*256

typedef __bf16 bf16x8 __attribute__((ext_vector_type(8)));
typedef float f32x4 __attribute__((ext_vector_type(4)));

__device__ inline unsigned short f2bf(float f) {
  unsigned u = __float_as_uint(f);
  u += 0x7fffu + ((u >> 16) & 1u);
  return (unsigned short)(u >> 16);
}
__device__ inline float bf2f(unsigned short s) {
  return __uint_as_float(((unsigned)s) << 16);
}
__device__ inline unsigned pack2(float a, float b) {
  return (unsigned)f2bf(a) | ((unsigned)f2bf(b) << 16);
}
__device__ inline void gload16(const void* g, void* l) {
  __builtin_amdgcn_global_load_lds(
      (const __attribute__((address_space(1))) void*)g,
      (__attribute__((address_space(3))) void*)l, 16, 0, 0);
}

// bijective XCD-aware remap (m204 formula)
__device__ inline void xcd_remap(int& bx, int& by) {
  const int gx = gridDim.x, gy = gridDim.y;
  const int nwg = gx * gy;
  int flat = blockIdx.y * gx + blockIdx.x;
  const int q = nwg >> 3, r = nwg & 7;
  const int xcd = flat & 7, lo = flat >> 3;
  int nf = (xcd < r) ? (xcd * (q + 1) + lo) : (r * (q + 1) + (xcd - r) * q + lo);
  bx = nf % gx; by = nf / gx;
}

__global__ void diag_kernel(float* out, float v) { out[0] = v; }

// ---------------- embed: x = prompts + pos_emb ----------------
__global__ void embed_kernel(const float4* __restrict__ p,
                             const float4* __restrict__ pe,
                             float4* __restrict__ x) {
  int r = blockIdx.x;
  int t = threadIdx.x;
  int l = r % LL;
  float4 a = p[(size_t)r*128 + t];
  float4 b = pe[(size_t)l*128 + t];
  float4 o; o.x=a.x+b.x; o.y=a.y+b.y; o.z=a.z+b.z; o.w=a.w+b.w;
  x[(size_t)r*128 + t] = o;
}

// ---------------- lengths = argmax(tokens)+1 ----------------
__global__ void lengths_kernel(const int* __restrict__ tok, int* __restrict__ len) {
  int b = blockIdx.x; int lane = threadIdx.x;
  int bv = -2147483647, bi = 0;
  for (int j = lane; j < LL; j += 64) {
    int v = tok[b*LL + j];
    if (v > bv) { bv = v; bi = j; }
  }
  for (int off = 32; off; off >>= 1) {
    int ov = __shfl_down(bv, off);
    int oi = __shfl_down(bi, off);
    if (ov > bv || (ov == bv && oi < bi)) { bv = ov; bi = oi; }
  }
  if (lane == 0) len[b] = bi + 1;
}

// mask value per reference where-chain (P=1, C=10 -> [1,11))
__device__ inline float maskv(int i, int j, int Lb) {
  const float NEG = -1e30f;
  float m = (j > i) ? NEG : 0.f;
  bool ctx = (i >= 1 && i < 11);
  if (ctx && j < Lb) m = 0.f;
  if (i >= 11 && i < Lb && j >= 1 && j < 11) m = NEG;
  if (ctx && j >= 1 && j < 11) m = NEG;
  if (j >= Lb) m = NEG;
  bool eot = (i == Lb - 1);
  if (eot && j < 11) m = 0.f;
  if (eot && j >= 11 && j < Lb) m = 0.1f;
  return m;
}

// ---------------- f32 -> bf16 convert ----------------
__global__ void cvt_kernel(const float4* __restrict__ s, uint2* __restrict__ d, int n4) {
  for (int i = blockIdx.x*blockDim.x + threadIdx.x; i < n4; i += gridDim.x*blockDim.x) {
    float4 v = s[i];
    uint2 o; o.x = pack2(v.x, v.y); o.y = pack2(v.z, v.w);
    d[i] = o;
  }
}

// ---------------- transpose text_projection (D,PROJ) -> W[PROJ][D] bf16 ----------------
__global__ void tpT_kernel(const float* __restrict__ tp, unsigned short* __restrict__ W) {
  int p = blockIdx.x;
  for (int d = threadIdx.x; d < DD; d += 256)
    W[(size_t)p*DD + d] = f2bf(tp[(size_t)d*DD + p]);
}

// ---------------- LayerNorm row of 512 -> bf16 (one wave per row) ----------------
__global__ __launch_bounds__(256) void ln_kernel(const float* __restrict__ X,
    const float* __restrict__ w, const float* __restrict__ bia,
    unsigned short* __restrict__ Oh) {
  int row = blockIdx.x*4 + (threadIdx.x >> 6);
  int lane = threadIdx.x & 63;
  const float* xr = X + (size_t)row*DD + lane*8;
  float4 v0 = *(const float4*)xr;
  float4 v1 = *(const float4*)(xr+4);
  float s = v0.x+v0.y+v0.z+v0.w+v1.x+v1.y+v1.z+v1.w;
  float q = v0.x*v0.x+v0.y*v0.y+v0.z*v0.z+v0.w*v0.w
          + v1.x*v1.x+v1.y*v1.y+v1.z*v1.z+v1.w*v1.w;
  for (int off = 1; off < 64; off <<= 1) { s += __shfl_xor(s, off); q += __shfl_xor(q, off); }
  float mu = s * (1.f/DD);
  float var = q * (1.f/DD) - mu*mu;
  float rs = rsqrtf(var + 1e-5f);
  const float* wp = w + lane*8; const float* bp = bia + lane*8;
  float4 w0 = *(const float4*)wp;  float4 w1 = *(const float4*)(wp+4);
  float4 b0 = *(const float4*)bp;  float4 b1 = *(const float4*)(bp+4);
  float o0 = (v0.x-mu)*rs*w0.x + b0.x;
  float o1 = (v0.y-mu)*rs*w0.y + b0.y;
  float o2 = (v0.z-mu)*rs*w0.z + b0.z;
  float o3 = (v0.w-mu)*rs*w0.w + b0.w;
  float o4 = (v1.x-mu)*rs*w1.x + b1.x;
  float o5 = (v1.y-mu)*rs*w1.y + b1.y;
  float o6 = (v1.z-mu)*rs*w1.z + b1.z;
  float o7 = (v1.w-mu)*rs*w1.w + b1.w;
  uint4 pk; pk.x = pack2(o0,o1); pk.y = pack2(o2,o3); pk.z = pack2(o4,o5); pk.w = pack2(o6,o7);
  *(uint4*)(Oh + (size_t)row*DD + lane*8) = pk;
}

// ---------------- final LN at eot row per batch ----------------
__global__ void eot_ln_kernel(const float* __restrict__ X, const int* __restrict__ len,
    const float* __restrict__ w, const float* __restrict__ bia,
    unsigned short* __restrict__ Xe) {
  int b = blockIdx.x; int lane = threadIdx.x;
  int row = len[b] - 1;
  const float* xr = X + ((size_t)b*LL + row)*DD + lane*8;
  float4 v0 = *(const float4*)xr;
  float4 v1 = *(const float4*)(xr+4);
  float s = v0.x+v0.y+v0.z+v0.w+v1.x+v1.y+v1.z+v1.w;
  float q = v0.x*v0.x+v0.y*v0.y+v0.z*v0.z+v0.w*v0.w
          + v1.x*v1.x+v1.y*v1.y+v1.z*v1.z+v1.w*v1.w;
  for (int off = 1; off < 64; off <<= 1) { s += __shfl_xor(s, off); q += __shfl_xor(q, off); }
  float mu = s * (1.f/DD);
  float var = q * (1.f/DD) - mu*mu;
  float rs = rsqrtf(var + 1e-5f);
  const float* wp = w + lane*8; const float* bp = bia + lane*8;
  float4 w0 = *(const float4*)wp;  float4 w1 = *(const float4*)(wp+4);
  float4 b0 = *(const float4*)bp;  float4 b1 = *(const float4*)(bp+4);
  float o0 = (v0.x-mu)*rs*w0.x + b0.x;
  float o1 = (v0.y-mu)*rs*w0.y + b0.y;
  float o2 = (v0.z-mu)*rs*w0.z + b0.z;
  float o3 = (v0.w-mu)*rs*w0.w + b0.w;
  float o4 = (v1.x-mu)*rs*w1.x + b1.x;
  float o5 = (v1.y-mu)*rs*w1.y + b1.y;
  float o6 = (v1.z-mu)*rs*w1.z + b1.z;
  float o7 = (v1.w-mu)*rs*w1.w + b1.w;
  uint4 pk; pk.x = pack2(o0,o1); pk.y = pack2(o2,o3); pk.z = pack2(o4,o5); pk.w = pack2(o6,o7);
  *(uint4*)(Xe + (size_t)b*DD + lane*8) = pk;
}

// ---------------- 256x256 deep-pipelined GEMM: C[M,N] = A[M,K] @ W[N,K]^T ----------------
// T3+T4: double-buffered 128KB LDS, prefetch issued first, COUNTED s_waitcnt vmcnt(8)
// (waits only the previous tile's 8 loads; the prefetch stays in flight across the
// barrier). Raw s_barrier (no full drain). 8 waves (2M x 4N), 64 MFMA/wave/K-step.
// XOR swizzle both-sides (verified R5): global source unit ^= row&7, read unit ^= row&7.
// EPI 0: bias -> bf16. EPI 1: bias + gelu -> bf16. EPI 2: bias + residual += f32. EPI 3: plain f32.
template<int EPI>
__global__ __launch_bounds__(512) void gemm256(
    const unsigned short* __restrict__ A,
    const unsigned short* __restrict__ W,
    const float* __restrict__ bias,
    unsigned short* __restrict__ Ob,
    float* __restrict__ Of,
    int N, int K)
{
  __shared__ unsigned short As[2][16384];  // [buf][256][64]
  __shared__ unsigned short Bs[2][16384];
  int bx, by;
  xcd_remap(bx, by);
  const int tid = threadIdx.x;
  const int lane = tid & 63;
  const int wid = tid >> 6;          // 0..7
  const int wm = wid >> 2;           // 0..1 (M half: 128 rows)
  const int wn = wid & 3;            // 0..3 (N quarter: 64 cols)
  const int m0 = by * 256, n0 = bx * 256;

  f32x4 acc[8][4] = {};

  const int r0 = tid >> 3;                       // 0..63 (row in 64-row group)
  const int cb = (((tid & 7) ^ (r0 & 7)) * 8);   // swizzled source 16B-unit

  auto stage = [&](int buf, int k0) {
    #pragma unroll
    for (int g = 0; g < 4; ++g)
      gload16(A + (size_t)(m0 + g*64 + r0) * K + k0 + cb, &As[buf][g*4096 + tid*8]);
    #pragma unroll
    for (int g = 0; g < 4; ++g)
      gload16(W + (size_t)(n0 + g*64 + r0) * K + k0 + cb, &Bs[buf][g*4096 + tid*8]);
  };

  const int nt = K >> 6;
  stage(0, 0);

  const int c = lane & 15, gq = lane >> 4;
  int cur = 0;
  for (int t = 0; t < nt; ++t) {
    if (t + 1 < nt) {
      stage(cur ^ 1, (t + 1) << 6);                   // prefetch next (8 loads in flight)
      asm volatile("s_waitcnt vmcnt(8)" ::: "memory"); // wait ONLY previous tile's loads
    } else {
      asm volatile("s_waitcnt vmcnt(0)" ::: "memory");
    }
    __builtin_amdgcn_s_barrier();                      // tile[cur] visible to all waves
    __builtin_amdgcn_sched_barrier(0);
    #pragma unroll
    for (int kk = 0; kk < 2; ++kk) {
      const int usw = ((kk*4 + gq) ^ (c & 7)) * 8;
      bf16x8 af[8], bfr[4];
      #pragma unroll
      for (int mi = 0; mi < 8; ++mi)
        af[mi] = *(const bf16x8*)(&As[cur][(wm*128 + mi*16 + c)*64 + usw]);
      #pragma unroll
      for (int ni = 0; ni < 4; ++ni)
        bfr[ni] = *(const bf16x8*)(&Bs[cur][(wn*64 + ni*16 + c)*64 + usw]);
      #pragma unroll
      for (int mi = 0; mi < 8; ++mi)
        #pragma unroll
        for (int ni = 0; ni < 4; ++ni)
          acc[mi][ni] = __builtin_amdgcn_mfma_f32_16x16x32_bf16(af[mi], bfr[ni], acc[mi][ni], 0, 0, 0);
    }
    __builtin_amdgcn_sched_barrier(0);
    __builtin_amdgcn_s_barrier();                      // all done reading buf[cur] before overwrite
    cur ^= 1;
  }

  const int rb = m0 + wm*128 + gq*4;
  const int cbase = n0 + wn*64 + c;
  #pragma unroll
  for (int mi = 0; mi < 8; ++mi) {
    #pragma unroll
    for (int ni = 0; ni < 4; ++ni) {
      int col = cbase + ni*16;
      float bv = 0.f;
      if constexpr (EPI != 3) bv = bias[col];
      #pragma unroll
      for (int j = 0; j < 4; ++j) {
        int row = rb + mi*16 + j;
        float v = acc[mi][ni][j] + bv;
        size_t ix = (size_t)row*N + col;
        if constexpr (EPI == 0) {
          Ob[ix] = f2bf(v);
        } else if constexpr (EPI == 1) {
          float sg = 1.f/(1.f + __expf(-1.702f*v));
          Ob[ix] = f2bf(v*sg);
        } else if constexpr (EPI == 2) {
          Of[ix] += v;
        } else {
          Of[ix] = v;
        }
      }
    }
  }
}

// ---------------- MFMA attention: one block per (b_local, h) ----------------
#define QS 72    // q/k LDS row stride (elems); +8 pad -> conflict-free frag reads
#define VS 104   // vt/p LDS row stride (elems)

__global__ __launch_bounds__(256) void attn_mfma(
    const unsigned short* __restrict__ qkv,   // [chT][1536] chunk-local bf16
    const int* __restrict__ len,              // pre-offset to chunk's batches
    unsigned short* __restrict__ O)           // [chT][512] chunk-local bf16
{
  __shared__ __align__(16) unsigned short q_s[80*QS];
  __shared__ __align__(16) unsigned short k_s[80*QS];
  __shared__ __align__(16) unsigned short vt_s[64*VS];
  __shared__ __align__(16) unsigned short p_s[80*VS];
  const int bh = blockIdx.x;
  const int b = bh >> 3, h = bh & 7;
  const int tid = threadIdx.x, lane = tid & 63, g = lane >> 4, c = lane & 15;
  const int Lb = len[b];
  const size_t base = (size_t)b*LL*1536 + h*64;

  for (int idx = tid; idx < 80*64; idx += 256) {
    int l = idx >> 6, d = idx & 63;
    unsigned short qv = 0, kv = 0;
    if (l < LL) {
      size_t gaddr = base + (size_t)l*1536 + d;
      qv = f2bf(bf2f(qkv[gaddr]) * 0.125f);
      kv = qkv[gaddr + 512];
    }
    q_s[l*QS + d] = qv;
    k_s[l*QS + d] = kv;
  }
  for (int idx = tid; idx < 80*64; idx += 256) {
    int l = idx >> 6, d = idx & 63;
    unsigned short vv = 0;
    if (l < LL) vv = qkv[base + (size_t)l*1536 + 1024 + d];
    vt_s[d*VS + l] = vv;
  }
  if (tid < 64) {
    for (int j = 80; j < 96; ++j) vt_s[tid*VS + j] = 0;
  }
  for (int idx = tid; idx < 80*16; idx += 256) {
    int r = idx >> 4, cc = 80 + (idx & 15);
    p_s[r*VS + cc] = 0;
  }
  __syncthreads();

  for (int s = (tid >> 6); s < 5; s += 4) {
    const int m0 = s*16;
    bf16x8 aq0 = *(const bf16x8*)(q_s + (m0 + c)*QS + g*8);
    bf16x8 aq1 = *(const bf16x8*)(q_s + (m0 + c)*QS + 32 + g*8);
    f32x4 sc[5];
    #pragma unroll
    for (int nt = 0; nt < 5; ++nt) {
      bf16x8 bk0 = *(const bf16x8*)(k_s + (nt*16 + c)*QS + g*8);
      bf16x8 bk1 = *(const bf16x8*)(k_s + (nt*16 + c)*QS + 32 + g*8);
      f32x4 z = {};
      z = __builtin_amdgcn_mfma_f32_16x16x32_bf16(aq0, bk0, z, 0, 0, 0);
      sc[nt] = __builtin_amdgcn_mfma_f32_16x16x32_bf16(aq1, bk1, z, 0, 0, 0);
    }
    #pragma unroll
    for (int j = 0; j < 4; ++j) {
      int r = m0 + g*4 + j;
      float sv[5];
      float mx = -3.4e38f;
      #pragma unroll
      for (int nt = 0; nt < 5; ++nt) {
        sv[nt] = sc[nt][j] + maskv(r, nt*16 + c, Lb);
        mx = fmaxf(mx, sv[nt]);
      }
      mx = fmaxf(mx, __shfl_xor(mx, 1));
      mx = fmaxf(mx, __shfl_xor(mx, 2));
      mx = fmaxf(mx, __shfl_xor(mx, 4));
      mx = fmaxf(mx, __shfl_xor(mx, 8));
      float sum = 0.f;
      #pragma unroll
      for (int nt = 0; nt < 5; ++nt) { sv[nt] = __expf(sv[nt] - mx); sum += sv[nt]; }
      sum += __shfl_xor(sum, 1); sum += __shfl_xor(sum, 2);
      sum += __shfl_xor(sum, 4); sum += __shfl_xor(sum, 8);
      float inv = 1.f / sum;
      #pragma unroll
      for (int nt = 0; nt < 5; ++nt)
        p_s[r*VS + nt*16 + c] = f2bf(sv[nt] * inv);
    }
    f32x4 oa[4] = {};
    #pragma unroll
    for (int kk = 0; kk < 3; ++kk) {
      bf16x8 ap = *(const bf16x8*)(p_s + (m0 + c)*VS + kk*32 + g*8);
      #pragma unroll
      for (int nt = 0; nt < 4; ++nt) {
        bf16x8 bv = *(const bf16x8*)(vt_s + (nt*16 + c)*VS + kk*32 + g*8);
        oa[nt] = __builtin_amdgcn_mfma_f32_16x16x32_bf16(ap, bv, oa[nt], 0, 0, 0);
      }
    }
    #pragma unroll
    for (int nt = 0; nt < 4; ++nt) {
      #pragma unroll
      for (int j = 0; j < 4; ++j) {
        int r = m0 + g*4 + j;
        if (r < LL)
          O[((size_t)b*LL + r)*512 + h*64 + nt*16 + c] = f2bf(oa[nt][j]);
      }
    }
  }
}

extern "C" void kernel_launch(void* const* d_in, const int* in_sizes, int n_in,
                              void* d_out, int out_size, void* d_ws, size_t ws_size,
                              hipStream_t stream) {
  const float* prompts = (const float*)d_in[0];
  const float* pos_emb = (const float*)d_in[1];
  const int*   tokens  = (const int*)d_in[2];
  const float* ln1w    = (const float*)d_in[3];
  const float* ln1b    = (const float*)d_in[4];
  const float* inw     = (const float*)d_in[5];
  const float* inb     = (const float*)d_in[6];
  const float* opw     = (const float*)d_in[7];
  const float* opb     = (const float*)d_in[8];
  const float* ln2w    = (const float*)d_in[9];
  const float* ln2b    = (const float*)d_in[10];
  const float* fcw     = (const float*)d_in[11];
  const float* fcb     = (const float*)d_in[12];
  const float* cpw     = (const float*)d_in[13];
  const float* cpb     = (const float*)d_in[14];
  const float* lnfw    = (const float*)d_in[15];
  const float* lnfb    = (const float*)d_in[16];
  const float* tp      = (const float*)d_in[17];
  float* out = (float*)d_out;

  char* basep = (char*)d_ws;
  size_t off = 0;
  auto carve = [&](size_t bytes) {
    char* p = basep + off;
    off += (bytes + 255) & ~(size_t)255;
    return (void*)p;
  };
  float* x            = (float*)carve((size_t)NTOK*DD*4);            // 80.7 MB
  unsigned short* hb  = (unsigned short*)carve((size_t)NTOK*DD*2);   // 40.4 MB
  unsigned short* w_tp = (unsigned short*)carve((size_t)512*512*2);
  unsigned short* xe   = (unsigned short*)carve((size_t)BB*DD*2);
  int* len             = (int*)carve((size_t)BB*4);

  // ---- tier selection: chunk count + weight conversion strategy ----
  const size_t per_layer_w = (size_t)(1536*512 + 512*512 + 2048*512 + 512*2048);
  size_t rem = (ws_size > off) ? (ws_size - off) : 0;
  auto bigb = [&](int n){ return ((size_t)NTOK/n)*2048*2 + 1024; };
  const size_t wfull = per_layer_w * NLAYER * 2 + 2048;
  const size_t wrot  = per_layer_w * 2 + 2048;
  int nch; bool fullw;
  if      (rem >= bigb(1) + wfull) { nch = 1; fullw = true; }
  else if (rem >= bigb(2) + wfull) { nch = 2; fullw = true; }
  else if (rem >= bigb(4) + wfull) { nch = 4; fullw = true; }
  else if (rem >= bigb(2) + wrot)  { nch = 2; fullw = false; }
  else if (rem >= bigb(4) + wrot)  { nch = 4; fullw = false; }
  else {
    diag_kernel<<<1, 1, 0, stream>>>(out, 1000.0f + (float)(ws_size >> 20));
    return;
  }
  const int chT = NTOK / nch;   // divisible by 256 for nch in {1,2,4}? 39424/2=19712=77*256 ok; /4=9856=38.5*256 NOT
  // chT must divide by 256 for gemm256: nch=4 -> 9856 = 38.5*256 invalid; force nch<=2
  if (nch == 4) { nch = 2; }
  const int chT2 = NTOK / nch;
  const int chB = BB / nch;

  unsigned short* big = (unsigned short*)carve((size_t)chT2*2048*2);
  unsigned short *w_in, *w_op, *w_fc, *w_cp;
  size_t stride_in = (size_t)1536*512, stride_op = (size_t)512*512;
  size_t stride_fc = (size_t)2048*512, stride_cp = (size_t)512*2048;
  if (fullw) {
    w_in = (unsigned short*)carve(NLAYER*stride_in*2);
    w_op = (unsigned short*)carve(NLAYER*stride_op*2);
    w_fc = (unsigned short*)carve(NLAYER*stride_fc*2);
    w_cp = (unsigned short*)carve(NLAYER*stride_cp*2);
  } else {
    w_in = (unsigned short*)carve(stride_in*2);
    w_op = (unsigned short*)carve(stride_op*2);
    w_fc = (unsigned short*)carve(stride_fc*2);
    w_cp = (unsigned short*)carve(stride_cp*2);
    stride_in = stride_op = stride_fc = stride_cp = 0;
  }

  embed_kernel<<<NTOK, 128, 0, stream>>>((const float4*)prompts, (const float4*)pos_emb, (float4*)x);
  lengths_kernel<<<BB, 64, 0, stream>>>(tokens, len);
  tpT_kernel<<<512, 256, 0, stream>>>(tp, w_tp);

  if (fullw) {
    cvt_kernel<<<4096, 256, 0, stream>>>((const float4*)inw, (uint2*)w_in, NLAYER*1536*512/4);
    cvt_kernel<<<4096, 256, 0, stream>>>((const float4*)opw, (uint2*)w_op, NLAYER*512*512/4);
    cvt_kernel<<<4096, 256, 0, stream>>>((const float4*)fcw, (uint2*)w_fc, NLAYER*2048*512/4);
    cvt_kernel<<<4096, 256, 0, stream>>>((const float4*)cpw, (uint2*)w_cp, NLAYER*512*2048/4);
  }

  for (int l = 0; l < NLAYER; ++l) {
    if (!fullw) {
      cvt_kernel<<<512, 256, 0, stream>>>((const float4*)(inw + (size_t)l*1536*512), (uint2*)w_in, 1536*512/4);
      cvt_kernel<<<512, 256, 0, stream>>>((const float4*)(opw + (size_t)l*512*512), (uint2*)w_op, 512*512/4);
      cvt_kernel<<<512, 256, 0, stream>>>((const float4*)(fcw + (size_t)l*2048*512), (uint2*)w_fc, 2048*512/4);
      cvt_kernel<<<512, 256, 0, stream>>>((const float4*)(cpw + (size_t)l*512*2048), (uint2*)w_cp, 512*2048/4);
    }
    const unsigned short* lw_in = w_in + (size_t)l*stride_in;
    const unsigned short* lw_op = w_op + (size_t)l*stride_op;
    const unsigned short* lw_fc = w_fc + (size_t)l*stride_fc;
    const unsigned short* lw_cp = w_cp + (size_t)l*stride_cp;

    ln_kernel<<<NTOK/4, 256, 0, stream>>>(x, ln1w + l*DD, ln1b + l*DD, hb);
    for (int c = 0; c < nch; ++c) {
      gemm256<0><<<dim3(1536/256, chT2/256), 512, 0, stream>>>(
          hb + (size_t)c*chT2*DD, lw_in, inb + l*1536, big, nullptr, 1536, 512);
      attn_mfma<<<chB*HH, 256, 0, stream>>>(big, len + c*chB, hb + (size_t)c*chT2*DD);
    }
    gemm256<2><<<dim3(512/256, NTOK/256), 512, 0, stream>>>(
        hb, lw_op, opb + l*DD, nullptr, x, 512, 512);

    ln_kernel<<<NTOK/4, 256, 0, stream>>>(x, ln2w + l*DD, ln2b + l*DD, hb);
    for (int c = 0; c < nch; ++c) {
      gemm256<1><<<dim3(2048/256, chT2/256), 512, 0, stream>>>(
          hb + (size_t)c*chT2*DD, lw_fc, fcb + l*2048, big, nullptr, 2048, 512);
      gemm256<2><<<dim3(512/256, chT2/256), 512, 0, stream>>>(
          big, lw_cp, cpb + l*DD, nullptr, x + (size_t)c*chT2*DD, 512, 2048);
    }
  }

  eot_ln_kernel<<<BB, 64, 0, stream>>>(x, len, lnfw, lnfb, xe);
  gemm256<3><<<dim3(512/256, 512/256), 512, 0, stream>>>(
      xe, w_tp, nullptr, nullptr, out, 512, 512);
}

// Round 8
// 6578.584 us; speedup vs baseline: 1.2693x; 1.2693x over previous
//
#include <hip/hip_runtime.h>
#include <hip/hip_bf16.h>
#include <stdint.h>

#define BB 512
#define LL 77
#define DD 512
#define HH 8
#define NLAYER 12
#define NTOK (BB*LL)        // 39424 = 308*128

typedef __bf16 bf16x8 __attribute__((ext_vector_type(8)));
typedef float f32x4 __attribute__((ext_vector_type(4)));

__device__ inline unsigned short f2bf(float f) {
  unsigned u = __float_as_uint(f);
  u += 0x7fffu + ((u >> 16) & 1u);
  return (unsigned short)(u >> 16);
}
__device__ inline float bf2f(unsigned short s) {
  return __uint_as_float(((unsigned)s) << 16);
}
__device__ inline unsigned pack2(float a, float b) {
  return (unsigned)f2bf(a) | ((unsigned)f2bf(b) << 16);
}
__device__ inline void gload16(const void* g, void* l) {
  __builtin_amdgcn_global_load_lds(
      (const __attribute__((address_space(1))) void*)g,
      (__attribute__((address_space(3))) void*)l, 16, 0, 0);
}

// bijective XCD-aware remap (m204 formula)
__device__ inline void xcd_remap(int& bx, int& by) {
  const int gx = gridDim.x, gy = gridDim.y;
  const int nwg = gx * gy;
  int flat = blockIdx.y * gx + blockIdx.x;
  const int q = nwg >> 3, r = nwg & 7;
  const int xcd = flat & 7, lo = flat >> 3;
  int nf = (xcd < r) ? (xcd * (q + 1) + lo) : (r * (q + 1) + (xcd - r) * q + lo);
  bx = nf % gx; by = nf / gx;
}

__global__ void diag_kernel(float* out, float v) { out[0] = v; }

// ---------------- embed: x = prompts + pos_emb ----------------
__global__ void embed_kernel(const float4* __restrict__ p,
                             const float4* __restrict__ pe,
                             float4* __restrict__ x) {
  int r = blockIdx.x;
  int t = threadIdx.x;
  int l = r % LL;
  float4 a = p[(size_t)r*128 + t];
  float4 b = pe[(size_t)l*128 + t];
  float4 o; o.x=a.x+b.x; o.y=a.y+b.y; o.z=a.z+b.z; o.w=a.w+b.w;
  x[(size_t)r*128 + t] = o;
}

// ---------------- lengths = argmax(tokens)+1 ----------------
__global__ void lengths_kernel(const int* __restrict__ tok, int* __restrict__ len) {
  int b = blockIdx.x; int lane = threadIdx.x;
  int bv = -2147483647, bi = 0;
  for (int j = lane; j < LL; j += 64) {
    int v = tok[b*LL + j];
    if (v > bv) { bv = v; bi = j; }
  }
  for (int off = 32; off; off >>= 1) {
    int ov = __shfl_down(bv, off);
    int oi = __shfl_down(bi, off);
    if (ov > bv || (ov == bv && oi < bi)) { bv = ov; bi = oi; }
  }
  if (lane == 0) len[b] = bi + 1;
}

// mask value per reference where-chain (P=1, C=10 -> [1,11))
__device__ inline float maskv(int i, int j, int Lb) {
  const float NEG = -1e30f;
  float m = (j > i) ? NEG : 0.f;
  bool ctx = (i >= 1 && i < 11);
  if (ctx && j < Lb) m = 0.f;
  if (i >= 11 && i < Lb && j >= 1 && j < 11) m = NEG;
  if (ctx && j >= 1 && j < 11) m = NEG;
  if (j >= Lb) m = NEG;
  bool eot = (i == Lb - 1);
  if (eot && j < 11) m = 0.f;
  if (eot && j >= 11 && j < Lb) m = 0.1f;
  return m;
}

// ---------------- f32 -> bf16 convert ----------------
__global__ void cvt_kernel(const float4* __restrict__ s, uint2* __restrict__ d, int n4) {
  for (int i = blockIdx.x*blockDim.x + threadIdx.x; i < n4; i += gridDim.x*blockDim.x) {
    float4 v = s[i];
    uint2 o; o.x = pack2(v.x, v.y); o.y = pack2(v.z, v.w);
    d[i] = o;
  }
}

// ---------------- transpose text_projection (D,PROJ) -> W[PROJ][D] bf16 ----------------
__global__ void tpT_kernel(const float* __restrict__ tp, unsigned short* __restrict__ W) {
  int p = blockIdx.x;
  for (int d = threadIdx.x; d < DD; d += 256)
    W[(size_t)p*DD + d] = f2bf(tp[(size_t)d*DD + p]);
}

// ---------------- LayerNorm row of 512 -> bf16 (one wave per row) ----------------
__global__ __launch_bounds__(256) void ln_kernel(const float* __restrict__ X,
    const float* __restrict__ w, const float* __restrict__ bia,
    unsigned short* __restrict__ Oh) {
  int row = blockIdx.x*4 + (threadIdx.x >> 6);
  int lane = threadIdx.x & 63;
  const float* xr = X + (size_t)row*DD + lane*8;
  float4 v0 = *(const float4*)xr;
  float4 v1 = *(const float4*)(xr+4);
  float s = v0.x+v0.y+v0.z+v0.w+v1.x+v1.y+v1.z+v1.w;
  float q = v0.x*v0.x+v0.y*v0.y+v0.z*v0.z+v0.w*v0.w
          + v1.x*v1.x+v1.y*v1.y+v1.z*v1.z+v1.w*v1.w;
  for (int off = 1; off < 64; off <<= 1) { s += __shfl_xor(s, off); q += __shfl_xor(q, off); }
  float mu = s * (1.f/DD);
  float var = q * (1.f/DD) - mu*mu;
  float rs = rsqrtf(var + 1e-5f);
  const float* wp = w + lane*8; const float* bp = bia + lane*8;
  float4 w0 = *(const float4*)wp;  float4 w1 = *(const float4*)(wp+4);
  float4 b0 = *(const float4*)bp;  float4 b1 = *(const float4*)(bp+4);
  float o0 = (v0.x-mu)*rs*w0.x + b0.x;
  float o1 = (v0.y-mu)*rs*w0.y + b0.y;
  float o2 = (v0.z-mu)*rs*w0.z + b0.z;
  float o3 = (v0.w-mu)*rs*w0.w + b0.w;
  float o4 = (v1.x-mu)*rs*w1.x + b1.x;
  float o5 = (v1.y-mu)*rs*w1.y + b1.y;
  float o6 = (v1.z-mu)*rs*w1.z + b1.z;
  float o7 = (v1.w-mu)*rs*w1.w + b1.w;
  uint4 pk; pk.x = pack2(o0,o1); pk.y = pack2(o2,o3); pk.z = pack2(o4,o5); pk.w = pack2(o6,o7);
  *(uint4*)(Oh + (size_t)row*DD + lane*8) = pk;
}

// ---------------- final LN at eot row per batch ----------------
__global__ void eot_ln_kernel(const float* __restrict__ X, const int* __restrict__ len,
    const float* __restrict__ w, const float* __restrict__ bia,
    unsigned short* __restrict__ Xe) {
  int b = blockIdx.x; int lane = threadIdx.x;
  int row = len[b] - 1;
  const float* xr = X + ((size_t)b*LL + row)*DD + lane*8;
  float4 v0 = *(const float4*)xr;
  float4 v1 = *(const float4*)(xr+4);
  float s = v0.x+v0.y+v0.z+v0.w+v1.x+v1.y+v1.z+v1.w;
  float q = v0.x*v0.x+v0.y*v0.y+v0.z*v0.z+v0.w*v0.w
          + v1.x*v1.x+v1.y*v1.y+v1.z*v1.z+v1.w*v1.w;
  for (int off = 1; off < 64; off <<= 1) { s += __shfl_xor(s, off); q += __shfl_xor(q, off); }
  float mu = s * (1.f/DD);
  float var = q * (1.f/DD) - mu*mu;
  float rs = rsqrtf(var + 1e-5f);
  const float* wp = w + lane*8; const float* bp = bia + lane*8;
  float4 w0 = *(const float4*)wp;  float4 w1 = *(const float4*)(wp+4);
  float4 b0 = *(const float4*)bp;  float4 b1 = *(const float4*)(bp+4);
  float o0 = (v0.x-mu)*rs*w0.x + b0.x;
  float o1 = (v0.y-mu)*rs*w0.y + b0.y;
  float o2 = (v0.z-mu)*rs*w0.z + b0.z;
  float o3 = (v0.w-mu)*rs*w0.w + b0.w;
  float o4 = (v1.x-mu)*rs*w1.x + b1.x;
  float o5 = (v1.y-mu)*rs*w1.y + b1.y;
  float o6 = (v1.z-mu)*rs*w1.z + b1.z;
  float o7 = (v1.w-mu)*rs*w1.w + b1.w;
  uint4 pk; pk.x = pack2(o0,o1); pk.y = pack2(o2,o3); pk.z = pack2(o4,o5); pk.w = pack2(o6,o7);
  *(uint4*)(Xe + (size_t)b*DD + lane*8) = pk;
}

// ---------------- GEMM (R5-proven): C[M,N] = A[M,K] @ W[N,K]^T, BK=64, 32KB LDS ----------------
// EPI 0: bias -> bf16. EPI 1: bias + gelu -> bf16. EPI 2: bias + residual += f32. EPI 3: plain f32.
// 16B-unit XOR swizzle both-sides (verified: conflicts 1.5e7 -> 0).
template<int EPI>
__global__ __launch_bounds__(256, 4) void gemm_bt(
    const unsigned short* __restrict__ A,
    const unsigned short* __restrict__ W,
    const float* __restrict__ bias,
    unsigned short* __restrict__ Ob,
    float* __restrict__ Of,
    int N, int K)
{
  __shared__ unsigned short As[8192];  // [128][64]
  __shared__ unsigned short Bs[8192];  // [128][64]
  int bx, by;
  xcd_remap(bx, by);
  const int tid = threadIdx.x;
  const int lane = tid & 63;
  const int wid = tid >> 6;
  const int wr = wid >> 1, wc = wid & 1;
  const int m0 = by * 128, n0 = bx * 128;

  f32x4 acc[4][4] = {};

  const int r0 = tid >> 3;                       // 0..31 (row within 32-row group)
  const int cb = (((tid & 7) ^ (r0 & 7)) * 8);   // swizzled source 16B-unit

  for (int k0 = 0; k0 < K; k0 += 64) {
    #pragma unroll
    for (int g = 0; g < 4; ++g) {
      gload16(A + (size_t)(m0 + g*32 + r0) * K + k0 + cb, As + g*2048 + tid*8);
      gload16(W + (size_t)(n0 + g*32 + r0) * K + k0 + cb, Bs + g*2048 + tid*8);
    }
    __syncthreads();
    const int c = lane & 15, gq = lane >> 4;
    #pragma unroll
    for (int kk = 0; kk < 2; ++kk) {
      const int usw = ((kk*4 + gq) ^ (c & 7)) * 8;   // swizzled read unit
      bf16x8 af[4], bfr[4];
      #pragma unroll
      for (int mi = 0; mi < 4; ++mi)
        af[mi] = *(const bf16x8*)(As + (wr*64 + mi*16 + c)*64 + usw);
      #pragma unroll
      for (int ni = 0; ni < 4; ++ni)
        bfr[ni] = *(const bf16x8*)(Bs + (wc*64 + ni*16 + c)*64 + usw);
      #pragma unroll
      for (int mi = 0; mi < 4; ++mi)
        #pragma unroll
        for (int ni = 0; ni < 4; ++ni)
          acc[mi][ni] = __builtin_amdgcn_mfma_f32_16x16x32_bf16(af[mi], bfr[ni], acc[mi][ni], 0, 0, 0);
    }
    __syncthreads();
  }

  const int rbase = m0 + wr*64 + ((lane>>4)*4);
  const int cbase = n0 + wc*64 + (lane&15);
  #pragma unroll
  for (int mi = 0; mi < 4; ++mi) {
    #pragma unroll
    for (int ni = 0; ni < 4; ++ni) {
      int col = cbase + ni*16;
      float bv = 0.f;
      if constexpr (EPI != 3) bv = bias[col];
      #pragma unroll
      for (int j = 0; j < 4; ++j) {
        int row = rbase + mi*16 + j;
        float v = acc[mi][ni][j] + bv;
        size_t ix = (size_t)row*N + col;
        if constexpr (EPI == 0) {
          Ob[ix] = f2bf(v);
        } else if constexpr (EPI == 1) {
          float sg = 1.f/(1.f + __expf(-1.702f*v));
          Ob[ix] = f2bf(v*sg);
        } else if constexpr (EPI == 2) {
          Of[ix] += v;
        } else {
          Of[ix] = v;
        }
      }
    }
  }
}

// ---------------- MFMA attention: one block per (b_local, h) ----------------
#define QS 72    // q/k LDS row stride (elems); +8 pad -> conflict-free frag reads
#define VS 104   // vt/p LDS row stride (elems)

__global__ __launch_bounds__(256) void attn_mfma(
    const unsigned short* __restrict__ qkv,   // [chT][1536] chunk-local bf16
    const int* __restrict__ len,              // pre-offset to chunk's batches
    unsigned short* __restrict__ O)           // [chT][512] chunk-local bf16
{
  __shared__ __align__(16) unsigned short q_s[80*QS];
  __shared__ __align__(16) unsigned short k_s[80*QS];
  __shared__ __align__(16) unsigned short vt_s[64*VS];
  __shared__ __align__(16) unsigned short p_s[80*VS];
  const int bh = blockIdx.x;
  const int b = bh >> 3, h = bh & 7;
  const int tid = threadIdx.x, lane = tid & 63, g = lane >> 4, c = lane & 15;
  const int Lb = len[b];
  const size_t base = (size_t)b*LL*1536 + h*64;

  for (int idx = tid; idx < 80*64; idx += 256) {
    int l = idx >> 6, d = idx & 63;
    unsigned short qv = 0, kv = 0;
    if (l < LL) {
      size_t gaddr = base + (size_t)l*1536 + d;
      qv = f2bf(bf2f(qkv[gaddr]) * 0.125f);
      kv = qkv[gaddr + 512];
    }
    q_s[l*QS + d] = qv;
    k_s[l*QS + d] = kv;
  }
  for (int idx = tid; idx < 80*64; idx += 256) {
    int l = idx >> 6, d = idx & 63;
    unsigned short vv = 0;
    if (l < LL) vv = qkv[base + (size_t)l*1536 + 1024 + d];
    vt_s[d*VS + l] = vv;
  }
  if (tid < 64) {
    for (int j = 80; j < 96; ++j) vt_s[tid*VS + j] = 0;
  }
  for (int idx = tid; idx < 80*16; idx += 256) {
    int r = idx >> 4, cc = 80 + (idx & 15);
    p_s[r*VS + cc] = 0;
  }
  __syncthreads();

  for (int s = (tid >> 6); s < 5; s += 4) {
    const int m0 = s*16;
    bf16x8 aq0 = *(const bf16x8*)(q_s + (m0 + c)*QS + g*8);
    bf16x8 aq1 = *(const bf16x8*)(q_s + (m0 + c)*QS + 32 + g*8);
    f32x4 sc[5];
    #pragma unroll
    for (int nt = 0; nt < 5; ++nt) {
      bf16x8 bk0 = *(const bf16x8*)(k_s + (nt*16 + c)*QS + g*8);
      bf16x8 bk1 = *(const bf16x8*)(k_s + (nt*16 + c)*QS + 32 + g*8);
      f32x4 z = {};
      z = __builtin_amdgcn_mfma_f32_16x16x32_bf16(aq0, bk0, z, 0, 0, 0);
      sc[nt] = __builtin_amdgcn_mfma_f32_16x16x32_bf16(aq1, bk1, z, 0, 0, 0);
    }
    #pragma unroll
    for (int j = 0; j < 4; ++j) {
      int r = m0 + g*4 + j;
      float sv[5];
      float mx = -3.4e38f;
      #pragma unroll
      for (int nt = 0; nt < 5; ++nt) {
        sv[nt] = sc[nt][j] + maskv(r, nt*16 + c, Lb);
        mx = fmaxf(mx, sv[nt]);
      }
      mx = fmaxf(mx, __shfl_xor(mx, 1));
      mx = fmaxf(mx, __shfl_xor(mx, 2));
      mx = fmaxf(mx, __shfl_xor(mx, 4));
      mx = fmaxf(mx, __shfl_xor(mx, 8));
      float sum = 0.f;
      #pragma unroll
      for (int nt = 0; nt < 5; ++nt) { sv[nt] = __expf(sv[nt] - mx); sum += sv[nt]; }
      sum += __shfl_xor(sum, 1); sum += __shfl_xor(sum, 2);
      sum += __shfl_xor(sum, 4); sum += __shfl_xor(sum, 8);
      float inv = 1.f / sum;
      #pragma unroll
      for (int nt = 0; nt < 5; ++nt)
        p_s[r*VS + nt*16 + c] = f2bf(sv[nt] * inv);
    }
    f32x4 oa[4] = {};
    #pragma unroll
    for (int kk = 0; kk < 3; ++kk) {
      bf16x8 ap = *(const bf16x8*)(p_s + (m0 + c)*VS + kk*32 + g*8);
      #pragma unroll
      for (int nt = 0; nt < 4; ++nt) {
        bf16x8 bv = *(const bf16x8*)(vt_s + (nt*16 + c)*VS + kk*32 + g*8);
        oa[nt] = __builtin_amdgcn_mfma_f32_16x16x32_bf16(ap, bv, oa[nt], 0, 0, 0);
      }
    }
    #pragma unroll
    for (int nt = 0; nt < 4; ++nt) {
      #pragma unroll
      for (int j = 0; j < 4; ++j) {
        int r = m0 + g*4 + j;
        if (r < LL)
          O[((size_t)b*LL + r)*512 + h*64 + nt*16 + c] = f2bf(oa[nt][j]);
      }
    }
  }
}

extern "C" void kernel_launch(void* const* d_in, const int* in_sizes, int n_in,
                              void* d_out, int out_size, void* d_ws, size_t ws_size,
                              hipStream_t stream) {
  const float* prompts = (const float*)d_in[0];
  const float* pos_emb = (const float*)d_in[1];
  const int*   tokens  = (const int*)d_in[2];
  const float* ln1w    = (const float*)d_in[3];
  const float* ln1b    = (const float*)d_in[4];
  const float* inw     = (const float*)d_in[5];
  const float* inb     = (const float*)d_in[6];
  const float* opw     = (const float*)d_in[7];
  const float* opb     = (const float*)d_in[8];
  const float* ln2w    = (const float*)d_in[9];
  const float* ln2b    = (const float*)d_in[10];
  const float* fcw     = (const float*)d_in[11];
  const float* fcb     = (const float*)d_in[12];
  const float* cpw     = (const float*)d_in[13];
  const float* cpb     = (const float*)d_in[14];
  const float* lnfw    = (const float*)d_in[15];
  const float* lnfb    = (const float*)d_in[16];
  const float* tp      = (const float*)d_in[17];
  float* out = (float*)d_out;

  char* basep = (char*)d_ws;
  size_t off = 0;
  auto carve = [&](size_t bytes) {
    char* p = basep + off;
    off += (bytes + 255) & ~(size_t)255;
    return (void*)p;
  };
  float* x            = (float*)carve((size_t)NTOK*DD*4);            // 80.7 MB
  unsigned short* hb  = (unsigned short*)carve((size_t)NTOK*DD*2);   // 40.4 MB
  unsigned short* w_tp = (unsigned short*)carve((size_t)512*512*2);
  unsigned short* xe   = (unsigned short*)carve((size_t)BB*DD*2);
  int* len             = (int*)carve((size_t)BB*4);

  // ---- tier selection: PREFER LARGE GRIDS (nch=1) over pre-converted weights ----
  const size_t per_layer_w = (size_t)(1536*512 + 512*512 + 2048*512 + 512*2048);
  size_t rem = (ws_size > off) ? (ws_size - off) : 0;
  auto bigb = [&](int n){ return ((size_t)NTOK/n)*2048*2 + 1024; };
  const size_t wfull = per_layer_w * NLAYER * 2 + 2048;
  const size_t wrot  = per_layer_w * 2 + 2048;
  int nch; bool fullw;
  if      (rem >= bigb(1) + wfull) { nch = 1; fullw = true; }
  else if (rem >= bigb(1) + wrot)  { nch = 1; fullw = false; }
  else if (rem >= bigb(2) + wfull) { nch = 2; fullw = true; }
  else if (rem >= bigb(2) + wrot)  { nch = 2; fullw = false; }
  else if (rem >= bigb(4) + wrot)  { nch = 4; fullw = false; }
  else {
    diag_kernel<<<1, 1, 0, stream>>>(out, 1000.0f + (float)(ws_size >> 20));
    return;
  }
  const int chT = NTOK / nch;   // 39424 / 19712 / 9856 — all divisible by 128
  const int chB = BB / nch;

  unsigned short* big = (unsigned short*)carve((size_t)chT*2048*2);
  unsigned short *w_in, *w_op, *w_fc, *w_cp;
  size_t stride_in = (size_t)1536*512, stride_op = (size_t)512*512;
  size_t stride_fc = (size_t)2048*512, stride_cp = (size_t)512*2048;
  if (fullw) {
    w_in = (unsigned short*)carve(NLAYER*stride_in*2);
    w_op = (unsigned short*)carve(NLAYER*stride_op*2);
    w_fc = (unsigned short*)carve(NLAYER*stride_fc*2);
    w_cp = (unsigned short*)carve(NLAYER*stride_cp*2);
  } else {
    w_in = (unsigned short*)carve(stride_in*2);
    w_op = (unsigned short*)carve(stride_op*2);
    w_fc = (unsigned short*)carve(stride_fc*2);
    w_cp = (unsigned short*)carve(stride_cp*2);
    stride_in = stride_op = stride_fc = stride_cp = 0;
  }

  embed_kernel<<<NTOK, 128, 0, stream>>>((const float4*)prompts, (const float4*)pos_emb, (float4*)x);
  lengths_kernel<<<BB, 64, 0, stream>>>(tokens, len);
  tpT_kernel<<<512, 256, 0, stream>>>(tp, w_tp);

  if (fullw) {
    cvt_kernel<<<4096, 256, 0, stream>>>((const float4*)inw, (uint2*)w_in, NLAYER*1536*512/4);
    cvt_kernel<<<4096, 256, 0, stream>>>((const float4*)opw, (uint2*)w_op, NLAYER*512*512/4);
    cvt_kernel<<<4096, 256, 0, stream>>>((const float4*)fcw, (uint2*)w_fc, NLAYER*2048*512/4);
    cvt_kernel<<<4096, 256, 0, stream>>>((const float4*)cpw, (uint2*)w_cp, NLAYER*512*2048/4);
  }

  for (int l = 0; l < NLAYER; ++l) {
    if (!fullw) {
      cvt_kernel<<<512, 256, 0, stream>>>((const float4*)(inw + (size_t)l*1536*512), (uint2*)w_in, 1536*512/4);
      cvt_kernel<<<512, 256, 0, stream>>>((const float4*)(opw + (size_t)l*512*512), (uint2*)w_op, 512*512/4);
      cvt_kernel<<<512, 256, 0, stream>>>((const float4*)(fcw + (size_t)l*2048*512), (uint2*)w_fc, 2048*512/4);
      cvt_kernel<<<512, 256, 0, stream>>>((const float4*)(cpw + (size_t)l*512*2048), (uint2*)w_cp, 512*2048/4);
    }
    const unsigned short* lw_in = w_in + (size_t)l*stride_in;
    const unsigned short* lw_op = w_op + (size_t)l*stride_op;
    const unsigned short* lw_fc = w_fc + (size_t)l*stride_fc;
    const unsigned short* lw_cp = w_cp + (size_t)l*stride_cp;

    ln_kernel<<<NTOK/4, 256, 0, stream>>>(x, ln1w + l*DD, ln1b + l*DD, hb);
    for (int c = 0; c < nch; ++c) {
      gemm_bt<0><<<dim3(1536/128, chT/128), 256, 0, stream>>>(
          hb + (size_t)c*chT*DD, lw_in, inb + l*1536, big, nullptr, 1536, 512);
      attn_mfma<<<chB*HH, 256, 0, stream>>>(big, len + c*chB, hb + (size_t)c*chT*DD);
    }
    gemm_bt<2><<<dim3(512/128, NTOK/128), 256, 0, stream>>>(
        hb, lw_op, opb + l*DD, nullptr, x, 512, 512);

    ln_kernel<<<NTOK/4, 256, 0, stream>>>(x, ln2w + l*DD, ln2b + l*DD, hb);
    for (int c = 0; c < nch; ++c) {
      gemm_bt<1><<<dim3(2048/128, chT/128), 256, 0, stream>>>(
          hb + (size_t)c*chT*DD, lw_fc, fcb + l*2048, big, nullptr, 2048, 512);
      gemm_bt<2><<<dim3(512/128, chT/128), 256, 0, stream>>>(
          big, lw_cp, cpb + l*DD, nullptr, x + (size_t)c*chT*DD, 512, 2048);
    }
  }

  eot_ln_kernel<<<BB, 64, 0, stream>>>(x, len, lnfw, lnfb, xe);
  gemm_bt<3><<<dim3(512/128, 512/128), 256, 0, stream>>>(
      xe, w_tp, nullptr, nullptr, out, 512, 512);
}